// Round 1
// baseline (38.995 us; speedup 1.0000x reference)
//
#include <hip/hip_runtime.h>

#define L 24
#define W 24
#define H 24
#define C 32
#define K 5
#define P 2
#define ZP (H + 2*P)        // 28  padded z-extent
#define NBSZ (K*K*ZP)       // 700 floats per block slab
#define JOUT (K*K*K)        // 125 offsets
#define PER_BLK (H*JOUT)    // 3000 output floats per (c,x,y)

__global__ __launch_bounds__(256) void selfcorr_kernel(const float* __restrict__ q,
                                                       float* __restrict__ out) {
    __shared__ float s_nb[NBSZ];   // [k0*5+k1][zz]  zero-padded neighbor rows
    __shared__ int   s_t[JOUT];    // t[j] = (k0*5+k1)*28 + k2

    const int blk = blockIdx.x;            // (c*24 + x)*24 + y
    const int y  = blk % W;
    const int cx = blk / W;
    const int x  = cx % L;
    const int c  = cx / L;
    const int tid = threadIdx.x;

    // Stage the 5x5x28 zero-padded slab: s_nb[kk*28+zz] = q[c, x+kk/5-2, y+kk%5-2, zz-2]
    for (int i = tid; i < NBSZ; i += 256) {
        int kk = i / ZP;
        int zz = i - kk * ZP;
        int gx = x + kk / K - P;
        int gy = y + kk % K - P;
        int gz = zz - P;
        float v = 0.0f;
        if ((unsigned)gx < (unsigned)L && (unsigned)gy < (unsigned)W && (unsigned)gz < (unsigned)H)
            v = q[((c * L + gx) * W + gy) * H + gz];
        s_nb[i] = v;
    }
    if (tid < JOUT) {
        int k0 = tid / 25;
        int r  = tid - k0 * 25;
        int k1 = r / 5;
        int k2 = r - k1 * 5;
        s_t[tid] = (k0 * K + k1) * ZP + k2;
    }
    __syncthreads();

    float* outp = out + (size_t)blk * PER_BLK;
    const int CENTER = (P * K + P) * ZP + P;   // 12*28+2 = 338

    #pragma unroll
    for (int i = 0; i < 3; ++i) {
        int e4 = i * 256 + tid;
        if (e4 < PER_BLK / 4) {              // 750 float4s
            int e = e4 * 4;
            float r0, r1, r2, r3;
            {
                int ee = e + 0;
                int z = ee / JOUT; int j = ee - z * JOUT;
                float p = s_nb[CENTER + z] * s_nb[s_t[j] + z];
                r0 = p > 0.0f ? p : 0.0f;
            }
            {
                int ee = e + 1;
                int z = ee / JOUT; int j = ee - z * JOUT;
                float p = s_nb[CENTER + z] * s_nb[s_t[j] + z];
                r1 = p > 0.0f ? p : 0.0f;
            }
            {
                int ee = e + 2;
                int z = ee / JOUT; int j = ee - z * JOUT;
                float p = s_nb[CENTER + z] * s_nb[s_t[j] + z];
                r2 = p > 0.0f ? p : 0.0f;
            }
            {
                int ee = e + 3;
                int z = ee / JOUT; int j = ee - z * JOUT;
                float p = s_nb[CENTER + z] * s_nb[s_t[j] + z];
                r3 = p > 0.0f ? p : 0.0f;
            }
            float4 v = make_float4(r0, r1, r2, r3);
            *reinterpret_cast<float4*>(outp + e) = v;
        }
    }
}

extern "C" void kernel_launch(void* const* d_in, const int* in_sizes, int n_in,
                              void* d_out, int out_size, void* d_ws, size_t ws_size,
                              hipStream_t stream) {
    const float* q = (const float*)d_in[0];
    float* out = (float*)d_out;
    const int nblk = C * L * W;   // 18432
    selfcorr_kernel<<<nblk, 256, 0, stream>>>(q, out);
}